// Round 4
// baseline (1428.351 us; speedup 1.0000x reference)
//
#include <hip/hip_runtime.h>

#define EPS 1e-9f

constexpr int B_ = 8, N_ = 2048, M_ = 2048;
constexpr int THREADS = 256;
constexpr int WAVES = THREADS / 64;                     // 4
constexpr int ROWS_PER_WAVE = 4;
constexpr int ROWS_PER_BLOCK = WAVES * ROWS_PER_WAVE;   // 16
constexpr int BLOCKS_PER_BATCH = N_ / ROWS_PER_BLOCK;   // 128
constexpr int GRID = B_ * BLOCKS_PER_BATCH;             // 1024

__global__ __launch_bounds__(THREADS) void init_kernel(float* rL, float* rR0,
                                                       float* ss0, float* ss1,
                                                       float* out) {
    int i = blockIdx.x * blockDim.x + threadIdx.x;
    if (i < B_ * N_) { rL[i] = 1.f; rR0[i] = 1.f; ss0[i] = 0.f; ss1[i] = 0.f; }
    if (i < B_) out[i] = 0.f;
}

// Phase 1: per row n: rowsum = sum_m exp(L*d2)*rR[m];
//          ss[m] += sum_n e[n,m] * rL[n]/(rowsum+EPS)
// Rows processed in PAIRS per sp[m] load (halves LDS traffic, 2 indep chains).
// exp via raw v_exp_f32 with log2e folded into l2 host-side.
__global__ __launch_bounds__(THREADS, 3) void phase1(
        const float* __restrict__ xyz1, const float* __restrict__ xyz2,
        const float* __restrict__ rL, const float* __restrict__ rR,
        float* __restrict__ ss, float* __restrict__ rowsum_g, float l2)
{
    __shared__ float4 sp[M_];                 // 32 KB: x,y,z,rR -> later ssl[4][M_]
    float* ssl = (float*)sp;                  // overlay after main loop
    const int b  = blockIdx.x / BLOCKS_PER_BATCH;
    const int n0 = (blockIdx.x % BLOCKS_PER_BATCH) * ROWS_PER_BLOCK;
    const int tid = threadIdx.x;

    const float* x2  = xyz2 + (size_t)b * M_ * 3;
    const float* rrb = rR + b * M_;
    for (int m = tid; m < M_; m += THREADS)
        sp[m] = make_float4(x2[3*m], x2[3*m+1], x2[3*m+2], rrb[m]);
    __syncthreads();

    const int wave = tid >> 6, lane = tid & 63;
    const int nw = n0 + wave * ROWS_PER_WAVE;

    float ssp[32];
    #pragma unroll
    for (int k = 0; k < 32; ++k) ssp[k] = 0.f;

    #pragma unroll 1
    for (int r = 0; r < ROWS_PER_WAVE; r += 2) {
        const int idx0 = b * N_ + nw + r;
        const int idx1 = idx0 + 1;
        const float* q0 = xyz1 + (size_t)idx0 * 3;
        const float* q1 = xyz1 + (size_t)idx1 * 3;
        const float x0 = q0[0], y0 = q0[1], z0 = q0[2];
        const float x1 = q1[0], y1 = q1[1], z1 = q1[2];
        const float rl0 = rL[idx0], rl1 = rL[idx1];

        float a0[32], a1[32];
        float p0 = 0.f, p1 = 0.f;
        #pragma unroll
        for (int k = 0; k < 32; ++k) {
            const float4 p = sp[lane + (k << 6)];
            const float dx0 = x0 - p.x, dy0 = y0 - p.y, dz0 = z0 - p.z;
            const float dx1 = x1 - p.x, dy1 = y1 - p.y, dz1 = z1 - p.z;
            const float d20 = dx0*dx0 + dy0*dy0 + dz0*dz0;
            const float d21 = dx1*dx1 + dy1*dy1 + dz1*dz1;
            const float e0 = __builtin_amdgcn_exp2f(l2 * d20) * p.w;
            const float e1 = __builtin_amdgcn_exp2f(l2 * d21) * p.w;
            a0[k] = e0; p0 += e0;
            a1[k] = e1; p1 += e1;
        }
        #pragma unroll
        for (int off = 32; off >= 1; off >>= 1) {
            p0 += __shfl_xor(p0, off, 64);
            p1 += __shfl_xor(p1, off, 64);
        }
        if (lane == 0) { rowsum_g[idx0] = p0; rowsum_g[idx1] = p1; }
        const float f0 = rl0 / (p0 + EPS);
        const float f1 = rl1 / (p1 + EPS);
        #pragma unroll
        for (int k = 0; k < 32; ++k)
            ssp[k] += a0[k] * f0 + a1[k] * f1;
    }

    __syncthreads();   // sp reads complete everywhere; safe to overlay
    #pragma unroll
    for (int k = 0; k < 32; ++k)
        ssl[wave * M_ + lane + (k << 6)] = ssp[k];
    __syncthreads();

    for (int m = tid; m < M_; m += THREADS) {
        const float s = ssl[0 * M_ + m] + ssl[1 * M_ + m]
                      + ssl[2 * M_ + m] + ssl[3 * M_ + m];
        atomicAdd(&ss[b * M_ + m], s);
    }
}

// Phase 2: g[m] = rR[m]*min(rR/(ss+EPS),1); per row: cost += f*sum(e*g*dist);
//          rL[n] = max(rL - f*sum(e*g), 0).
// All 4 rows of the wave computed per sp[m] load (LDS traffic /4, 8 indep acc
// chains). Raw v_exp_f32 / v_sqrt_f32. Designated block per batch also writes
// rR_next = max(rR - ss*ratio, 0) and zeroes ss_next (replaces update_rR).
__global__ __launch_bounds__(THREADS, 4) void phase2(
        const float* __restrict__ xyz1, const float* __restrict__ xyz2,
        float* __restrict__ rL, const float* __restrict__ rR,
        float* __restrict__ rR_next, const float* __restrict__ ss,
        float* __restrict__ ss_next, const float* __restrict__ rowsum_g,
        float* __restrict__ out, float l2)
{
    __shared__ float4 sp[M_];        // x,y,z,g
    __shared__ float  wcost[WAVES];
    const int b  = blockIdx.x / BLOCKS_PER_BATCH;
    const int blk_in_b = blockIdx.x % BLOCKS_PER_BATCH;
    const int n0 = blk_in_b * ROWS_PER_BLOCK;
    const int tid = threadIdx.x;
    const bool designated = (blk_in_b == 0);

    const float* x2 = xyz2 + (size_t)b * M_ * 3;
    for (int m = tid; m < M_; m += THREADS) {
        const float rr = rR[b * M_ + m];
        const float s  = ss[b * M_ + m];
        const float ratio = fminf(rr / (s + EPS), 1.f);
        sp[m] = make_float4(x2[3*m], x2[3*m+1], x2[3*m+2], rr * ratio);
        if (designated) {
            rR_next[b * M_ + m] = fmaxf(rr - s * ratio, 0.f);
            ss_next[b * M_ + m] = 0.f;
        }
    }
    __syncthreads();

    const int wave = tid >> 6, lane = tid & 63;
    const int nw = n0 + wave * ROWS_PER_WAVE;

    float xv[ROWS_PER_WAVE], yv[ROWS_PER_WAVE], zv[ROWS_PER_WAVE];
    float accd[ROWS_PER_WAVE], accc[ROWS_PER_WAVE];
    #pragma unroll
    for (int r = 0; r < ROWS_PER_WAVE; ++r) {
        const float* q = xyz1 + (size_t)(b * N_ + nw + r) * 3;
        xv[r] = q[0]; yv[r] = q[1]; zv[r] = q[2];
        accd[r] = 0.f; accc[r] = 0.f;
    }

    #pragma unroll
    for (int k = 0; k < 32; ++k) {
        const float4 p = sp[lane + (k << 6)];
        #pragma unroll
        for (int r = 0; r < ROWS_PER_WAVE; ++r) {
            const float dx = xv[r] - p.x, dy = yv[r] - p.y, dz = zv[r] - p.z;
            const float d2 = dx*dx + dy*dy + dz*dz;
            const float e = __builtin_amdgcn_exp2f(l2 * d2) * p.w;
            accd[r] += e;
            accc[r] += e * __builtin_amdgcn_sqrtf(fmaxf(d2, 1e-20f));
        }
    }

    #pragma unroll
    for (int r = 0; r < ROWS_PER_WAVE; ++r) {
        #pragma unroll
        for (int off = 32; off >= 1; off >>= 1) {
            accd[r] += __shfl_xor(accd[r], off, 64);
            accc[r] += __shfl_xor(accc[r], off, 64);
        }
    }

    float cwave = 0.f;
    if (lane == 0) {
        #pragma unroll
        for (int r = 0; r < ROWS_PER_WAVE; ++r) {
            const int idx = b * N_ + nw + r;
            const float rl = rL[idx];
            const float f = rl / (rowsum_g[idx] + EPS);
            rL[idx] = fmaxf(rl - f * accd[r], 0.f);
            cwave += f * accc[r];
        }
        wcost[wave] = cwave;
    }
    __syncthreads();
    if (tid == 0)
        atomicAdd(&out[b], wcost[0] + wcost[1] + wcost[2] + wcost[3]);
}

extern "C" void kernel_launch(void* const* d_in, const int* in_sizes, int n_in,
                              void* d_out, int out_size, void* d_ws, size_t ws_size,
                              hipStream_t stream) {
    const float* xyz1 = (const float*)d_in[0];
    const float* xyz2 = (const float*)d_in[1];
    float* out = (float*)d_out;
    float* ws = (float*)d_ws;
    const int SZ = B_ * N_;        // == B_*M_ == 16384
    float* rL     = ws;
    float* rowsum = ws + SZ;
    float* rRb[2] = { ws + 2 * SZ, ws + 3 * SZ };
    float* ssb[2] = { ws + 4 * SZ, ws + 5 * SZ };

    init_kernel<<<(SZ + THREADS - 1) / THREADS, THREADS, 0, stream>>>(
        rL, rRb[0], ssb[0], ssb[1], out);

    // levels -4^j for j=7..-1, then 0; pre-multiplied by log2(e) so the
    // kernel computes exp(L*d2) as exp2(l2*d2) with a single v_exp_f32.
    constexpr float LOG2E = 1.4426950408889634f;
    static const float levels[10] = {
        -16384.f, -4096.f, -1024.f, -256.f, -64.f,
        -16.f, -4.f, -1.f, -0.25f, 0.f
    };
    for (int s = 0; s < 10; ++s) {
        float* rR_cur  = rRb[s & 1];
        float* rR_next = rRb[(s + 1) & 1];
        float* ss_cur  = ssb[s & 1];
        float* ss_next = ssb[(s + 1) & 1];
        const float l2 = levels[s] * LOG2E;
        phase1<<<GRID, THREADS, 0, stream>>>(
            xyz1, xyz2, rL, rR_cur, ss_cur, rowsum, l2);
        phase2<<<GRID, THREADS, 0, stream>>>(
            xyz1, xyz2, rL, rR_cur, rR_next, ss_cur, ss_next, rowsum, out, l2);
    }
}

// Round 5
// 498.484 us; speedup vs baseline: 2.8654x; 2.8654x over previous
//
#include <hip/hip_runtime.h>

#define EPS 1e-9f

constexpr int B_ = 8, N_ = 2048, M_ = 2048;
constexpr int THREADS = 256;
constexpr int WAVES = THREADS / 64;                     // 4
constexpr int ROWS_PER_WAVE = 4;
constexpr int ROWS_PER_BLOCK = WAVES * ROWS_PER_WAVE;   // 16
constexpr int BLOCKS_PER_BATCH = N_ / ROWS_PER_BLOCK;   // 128
constexpr int GRID = B_ * BLOCKS_PER_BATCH;             // 1024 = 4 blocks/CU

__global__ __launch_bounds__(THREADS) void init_kernel(float* rL, float* rR0,
                                                       float* ss0, float* ss1,
                                                       float* out) {
    int i = blockIdx.x * blockDim.x + threadIdx.x;
    if (i < B_ * N_) { rL[i] = 1.f; rR0[i] = 1.f; ss0[i] = 0.f; ss1[i] = 0.f; }
    if (i < B_) out[i] = 0.f;
}

// Phase 1, two-pass recompute (NO per-element register storage -> no spills):
//   pass A: p[r] = sum_m exp2(l2*d2)*rR[m]            (rowsums)
//   pass B: ssp[k] += sum_r e(r,k)*f[r],  f=rL/(p+EPS)
// 4 rows per LDS load in both passes. Per-wave LDS slices overlaid on sp,
// then one global atomic per column per block.
__global__ __launch_bounds__(THREADS, 4) void phase1(
        const float* __restrict__ xyz1, const float* __restrict__ xyz2,
        const float* __restrict__ rL, const float* __restrict__ rR,
        float* __restrict__ ss, float* __restrict__ rowsum_g, float l2)
{
    __shared__ float4 sp[M_];                 // 32 KB: x,y,z,rR -> later ssl[4][M_]
    float* ssl = (float*)sp;                  // overlay after main loop
    const int b  = blockIdx.x / BLOCKS_PER_BATCH;
    const int n0 = (blockIdx.x % BLOCKS_PER_BATCH) * ROWS_PER_BLOCK;
    const int tid = threadIdx.x;

    const float* x2  = xyz2 + (size_t)b * M_ * 3;
    const float* rrb = rR + b * M_;
    for (int m = tid; m < M_; m += THREADS)
        sp[m] = make_float4(x2[3*m], x2[3*m+1], x2[3*m+2], rrb[m]);
    __syncthreads();

    const int wave = tid >> 6, lane = tid & 63;
    const int nw = n0 + wave * ROWS_PER_WAVE;

    float xv[ROWS_PER_WAVE], yv[ROWS_PER_WAVE], zv[ROWS_PER_WAVE];
    float p[ROWS_PER_WAVE];
    #pragma unroll
    for (int r = 0; r < ROWS_PER_WAVE; ++r) {
        const float* q = xyz1 + (size_t)(b * N_ + nw + r) * 3;
        xv[r] = q[0]; yv[r] = q[1]; zv[r] = q[2];
        p[r] = 0.f;
    }

    // Pass A: rowsums
    #pragma unroll
    for (int k = 0; k < 32; ++k) {
        const float4 c = sp[lane + (k << 6)];
        #pragma unroll
        for (int r = 0; r < ROWS_PER_WAVE; ++r) {
            const float dx = xv[r] - c.x, dy = yv[r] - c.y, dz = zv[r] - c.z;
            const float d2 = dx*dx + dy*dy + dz*dz;
            p[r] += __builtin_amdgcn_exp2f(l2 * d2) * c.w;
        }
    }
    #pragma unroll
    for (int r = 0; r < ROWS_PER_WAVE; ++r) {
        #pragma unroll
        for (int off = 32; off >= 1; off >>= 1)
            p[r] += __shfl_xor(p[r], off, 64);
    }
    float f[ROWS_PER_WAVE];
    #pragma unroll
    for (int r = 0; r < ROWS_PER_WAVE; ++r) {
        const int idx = b * N_ + nw + r;
        if (lane == 0) rowsum_g[idx] = p[r];
        f[r] = rL[idx] / (p[r] + EPS);
    }

    // Pass B: recompute e, accumulate per-lane column sums
    float ssp[32];
    #pragma unroll
    for (int k = 0; k < 32; ++k) {
        const float4 c = sp[lane + (k << 6)];
        float s = 0.f;
        #pragma unroll
        for (int r = 0; r < ROWS_PER_WAVE; ++r) {
            const float dx = xv[r] - c.x, dy = yv[r] - c.y, dz = zv[r] - c.z;
            const float d2 = dx*dx + dy*dy + dz*dz;
            s += __builtin_amdgcn_exp2f(l2 * d2) * f[r];
        }
        ssp[k] = s * c.w;
    }

    __syncthreads();   // sp reads complete everywhere; safe to overlay
    #pragma unroll
    for (int k = 0; k < 32; ++k)
        ssl[wave * M_ + lane + (k << 6)] = ssp[k];
    __syncthreads();

    for (int m = tid; m < M_; m += THREADS) {
        const float s = ssl[0 * M_ + m] + ssl[1 * M_ + m]
                      + ssl[2 * M_ + m] + ssl[3 * M_ + m];
        atomicAdd(&ss[b * M_ + m], s);
    }
}

// Phase 2: g[m] = rR[m]*min(rR/(ss+EPS),1); per row: cost += f*sum(e*g*dist);
//          rL[n] = max(rL - f*sum(e*g), 0).
// All 4 rows per sp[m] load; raw v_exp_f32/v_sqrt_f32. Designated block per
// batch writes rR_next = max(rR - ss*ratio, 0) and zeroes ss_next.
__global__ __launch_bounds__(THREADS, 4) void phase2(
        const float* __restrict__ xyz1, const float* __restrict__ xyz2,
        float* __restrict__ rL, const float* __restrict__ rR,
        float* __restrict__ rR_next, const float* __restrict__ ss,
        float* __restrict__ ss_next, const float* __restrict__ rowsum_g,
        float* __restrict__ out, float l2)
{
    __shared__ float4 sp[M_];        // x,y,z,g
    __shared__ float  wcost[WAVES];
    const int b  = blockIdx.x / BLOCKS_PER_BATCH;
    const int blk_in_b = blockIdx.x % BLOCKS_PER_BATCH;
    const int n0 = blk_in_b * ROWS_PER_BLOCK;
    const int tid = threadIdx.x;
    const bool designated = (blk_in_b == 0);

    const float* x2 = xyz2 + (size_t)b * M_ * 3;
    for (int m = tid; m < M_; m += THREADS) {
        const float rr = rR[b * M_ + m];
        const float s  = ss[b * M_ + m];
        const float ratio = fminf(rr / (s + EPS), 1.f);
        sp[m] = make_float4(x2[3*m], x2[3*m+1], x2[3*m+2], rr * ratio);
        if (designated) {
            rR_next[b * M_ + m] = fmaxf(rr - s * ratio, 0.f);
            ss_next[b * M_ + m] = 0.f;
        }
    }
    __syncthreads();

    const int wave = tid >> 6, lane = tid & 63;
    const int nw = n0 + wave * ROWS_PER_WAVE;

    float xv[ROWS_PER_WAVE], yv[ROWS_PER_WAVE], zv[ROWS_PER_WAVE];
    float accd[ROWS_PER_WAVE], accc[ROWS_PER_WAVE];
    #pragma unroll
    for (int r = 0; r < ROWS_PER_WAVE; ++r) {
        const float* q = xyz1 + (size_t)(b * N_ + nw + r) * 3;
        xv[r] = q[0]; yv[r] = q[1]; zv[r] = q[2];
        accd[r] = 0.f; accc[r] = 0.f;
    }

    #pragma unroll
    for (int k = 0; k < 32; ++k) {
        const float4 p = sp[lane + (k << 6)];
        #pragma unroll
        for (int r = 0; r < ROWS_PER_WAVE; ++r) {
            const float dx = xv[r] - p.x, dy = yv[r] - p.y, dz = zv[r] - p.z;
            const float d2 = dx*dx + dy*dy + dz*dz;
            const float e = __builtin_amdgcn_exp2f(l2 * d2) * p.w;
            accd[r] += e;
            accc[r] += e * __builtin_amdgcn_sqrtf(fmaxf(d2, 1e-20f));
        }
    }

    #pragma unroll
    for (int r = 0; r < ROWS_PER_WAVE; ++r) {
        #pragma unroll
        for (int off = 32; off >= 1; off >>= 1) {
            accd[r] += __shfl_xor(accd[r], off, 64);
            accc[r] += __shfl_xor(accc[r], off, 64);
        }
    }

    float cwave = 0.f;
    if (lane == 0) {
        #pragma unroll
        for (int r = 0; r < ROWS_PER_WAVE; ++r) {
            const int idx = b * N_ + nw + r;
            const float rl = rL[idx];
            const float f = rl / (rowsum_g[idx] + EPS);
            rL[idx] = fmaxf(rl - f * accd[r], 0.f);
            cwave += f * accc[r];
        }
        wcost[wave] = cwave;
    }
    __syncthreads();
    if (tid == 0)
        atomicAdd(&out[b], wcost[0] + wcost[1] + wcost[2] + wcost[3]);
}

extern "C" void kernel_launch(void* const* d_in, const int* in_sizes, int n_in,
                              void* d_out, int out_size, void* d_ws, size_t ws_size,
                              hipStream_t stream) {
    const float* xyz1 = (const float*)d_in[0];
    const float* xyz2 = (const float*)d_in[1];
    float* out = (float*)d_out;
    float* ws = (float*)d_ws;
    const int SZ = B_ * N_;        // == B_*M_ == 16384
    float* rL     = ws;
    float* rowsum = ws + SZ;
    float* rRb[2] = { ws + 2 * SZ, ws + 3 * SZ };
    float* ssb[2] = { ws + 4 * SZ, ws + 5 * SZ };

    init_kernel<<<(SZ + THREADS - 1) / THREADS, THREADS, 0, stream>>>(
        rL, rRb[0], ssb[0], ssb[1], out);

    // levels -4^j for j=7..-1, then 0; pre-multiplied by log2(e) so the
    // kernel computes exp(L*d2) as exp2(l2*d2) with a single v_exp_f32.
    constexpr float LOG2E = 1.4426950408889634f;
    static const float levels[10] = {
        -16384.f, -4096.f, -1024.f, -256.f, -64.f,
        -16.f, -4.f, -1.f, -0.25f, 0.f
    };
    for (int s = 0; s < 10; ++s) {
        float* rR_cur  = rRb[s & 1];
        float* rR_next = rRb[(s + 1) & 1];
        float* ss_cur  = ssb[s & 1];
        float* ss_next = ssb[(s + 1) & 1];
        const float l2 = levels[s] * LOG2E;
        phase1<<<GRID, THREADS, 0, stream>>>(
            xyz1, xyz2, rL, rR_cur, ss_cur, rowsum, l2);
        phase2<<<GRID, THREADS, 0, stream>>>(
            xyz1, xyz2, rL, rR_cur, rR_next, ss_cur, ss_next, rowsum, out, l2);
    }
}

// Round 6
// 450.375 us; speedup vs baseline: 3.1715x; 1.1068x over previous
//
#include <hip/hip_runtime.h>

#define EPS 1e-9f

constexpr int B_ = 8, N_ = 2048, M_ = 2048;
constexpr int THREADS = 256;
constexpr int WAVES = 4;
constexpr int RPW = 8;                       // rows per wave
constexpr int RPB = WAVES * RPW;             // 32 rows per block
constexpr int BPB = N_ / RPB;                // 64 blocks per batch
constexpr int GRID = B_ * BPB;               // 512 blocks = 2/CU

__global__ __launch_bounds__(THREADS) void init_kernel(float* rL, float* fb,
                                                       float* ss0, float* out) {
    int i = blockIdx.x * blockDim.x + threadIdx.x;
    if (i < B_ * N_) { rL[i] = 1.f; fb[i] = 0.f; ss0[i] = 0.f; }
    if (i < B_) out[i] = 0.f;
}

// One kernel per annealing step s: [phase2 of step s-1] + [phase1 of step s].
// Both g(s-1)=rR*ratio and rR(s)=max(rR-ss*ratio,0) are per-column functions of
// the globally-complete (rR(s-1), ss(s-1)) -> computed redundantly per block in
// the single staging pass. rL is updated in-register between the two parts
// (each block owns its rows for the whole schedule); f = rL/(rowsum+EPS) is
// passed to the next kernel via global. ss triple-buffered: this kernel
// atomically accumulates ss(s) into a buffer pre-zeroed by kernel s-1.
__global__ __launch_bounds__(THREADS, 2) void fused_step(
        const float* __restrict__ xyz1, const float* __restrict__ xyz2,
        float* __restrict__ rLb, float* __restrict__ fb,
        const float* __restrict__ rRp,   // rR(s-1) in   (unused if !has_p2)
        float* __restrict__ rRn_g,       // rR(s)  out   (designated block)
        const float* __restrict__ ssp_g, // ss(s-1) in   (unused if !has_p2)
        float* __restrict__ ssc_g,       // ss(s) atomic accumulate (pre-zeroed)
        float* __restrict__ ssz_g,       // ss(s+1) zeroed here for next kernel
        float* __restrict__ out,
        float l2p, float l2c, int has_p2, int has_p1)
{
    __shared__ float4 spg[M_];           // x,y,z,g   (32 KB) -> ssl overlay
    __shared__ float4 spr[M_];           // x,y,z,rn  (32 KB)
    __shared__ float  wcost[WAVES];
    float* ssl = (float*)spg;

    const int b   = blockIdx.x / BPB;
    const int blk = blockIdx.x % BPB;
    const int n0  = blk * RPB;
    const int tid = threadIdx.x;
    const bool designated = (blk == 0);

    // ---- staging: points + per-column factors for BOTH parts ----
    const float* x2 = xyz2 + (size_t)b * M_ * 3;
    for (int m = tid; m < M_; m += THREADS) {
        const float x = x2[3*m], y = x2[3*m+1], z = x2[3*m+2];
        float g = 0.f, rn = 1.f;
        if (has_p2) {
            const float rr = rRp[b * M_ + m];
            const float s  = ssp_g[b * M_ + m];
            const float ratio = fminf(rr / (s + EPS), 1.f);
            g  = rr * ratio;
            rn = fmaxf(rr - s * ratio, 0.f);
        }
        spg[m] = make_float4(x, y, z, g);
        spr[m] = make_float4(x, y, z, rn);
        if (designated) {
            if (has_p1) rRn_g[b * M_ + m] = rn;
            ssz_g[b * M_ + m] = 0.f;
        }
    }
    __syncthreads();

    const int wave = tid >> 6, lane = tid & 63;
    const int nw = n0 + wave * RPW;

    float xv[RPW], yv[RPW], zv[RPW];
    #pragma unroll
    for (int r = 0; r < RPW; ++r) {
        const float* q = xyz1 + (size_t)(b * N_ + nw + r) * 3;
        xv[r] = q[0]; yv[r] = q[1]; zv[r] = q[2];
    }

    // ---- phase2-part (level s-1): cost + rL update ----
    float rl_new[RPW];
    if (has_p2) {
        float accd[RPW], accc[RPW];
        #pragma unroll
        for (int r = 0; r < RPW; ++r) { accd[r] = 0.f; accc[r] = 0.f; }
        #pragma unroll
        for (int k = 0; k < 32; ++k) {
            const float4 c = spg[lane + (k << 6)];
            #pragma unroll
            for (int r = 0; r < RPW; ++r) {
                const float dx = xv[r]-c.x, dy = yv[r]-c.y, dz = zv[r]-c.z;
                const float d2 = dx*dx + dy*dy + dz*dz;
                const float e = __builtin_amdgcn_exp2f(l2p * d2) * c.w;
                accd[r] += e;
                accc[r] += e * __builtin_amdgcn_sqrtf(fmaxf(d2, 1e-20f));
            }
        }
        #pragma unroll
        for (int r = 0; r < RPW; ++r) {
            #pragma unroll
            for (int off = 32; off >= 1; off >>= 1) {
                accd[r] += __shfl_xor(accd[r], off, 64);
                accc[r] += __shfl_xor(accc[r], off, 64);
            }
        }
        float cw = 0.f;
        #pragma unroll
        for (int r = 0; r < RPW; ++r) {
            const int idx = b * N_ + nw + r;
            const float fo = fb[idx];               // f(s-1), broadcast load
            const float rl = rLb[idx];
            rl_new[r] = fmaxf(rl - fo * accd[r], 0.f);
            cw += fo * accc[r];
        }
        if (lane == 0) wcost[wave] = cw;
    } else {
        #pragma unroll
        for (int r = 0; r < RPW; ++r) rl_new[r] = 1.f;
        if (lane == 0) wcost[wave] = 0.f;
    }
    __syncthreads();   // wcost ready; also: all spg reads done (ssl overlay safe)
    if (tid == 0 && has_p2)
        atomicAdd(&out[b], wcost[0] + wcost[1] + wcost[2] + wcost[3]);

    // ---- phase1-part (level s): rowsums -> f, ss accumulate ----
    if (has_p1) {
        float p[RPW];
        #pragma unroll
        for (int r = 0; r < RPW; ++r) p[r] = 0.f;
        #pragma unroll
        for (int k = 0; k < 32; ++k) {
            const float4 c = spr[lane + (k << 6)];
            #pragma unroll
            for (int r = 0; r < RPW; ++r) {
                const float dx = xv[r]-c.x, dy = yv[r]-c.y, dz = zv[r]-c.z;
                const float d2 = dx*dx + dy*dy + dz*dz;
                p[r] += __builtin_amdgcn_exp2f(l2c * d2) * c.w;
            }
        }
        #pragma unroll
        for (int r = 0; r < RPW; ++r) {
            #pragma unroll
            for (int off = 32; off >= 1; off >>= 1)
                p[r] += __shfl_xor(p[r], off, 64);
        }
        float fn[RPW];
        #pragma unroll
        for (int r = 0; r < RPW; ++r)
            fn[r] = rl_new[r] / (p[r] + EPS);
        if (lane == 0) {
            #pragma unroll
            for (int r = 0; r < RPW; ++r) {
                const int idx = b * N_ + nw + r;
                fb[idx]  = fn[r];
                rLb[idx] = rl_new[r];
            }
        }
        // pass B: per-lane column sums (recompute e; no per-element storage)
        float ssp[32];
        #pragma unroll
        for (int k = 0; k < 32; ++k) {
            const float4 c = spr[lane + (k << 6)];
            float s = 0.f;
            #pragma unroll
            for (int r = 0; r < RPW; ++r) {
                const float dx = xv[r]-c.x, dy = yv[r]-c.y, dz = zv[r]-c.z;
                const float d2 = dx*dx + dy*dy + dz*dz;
                s += __builtin_amdgcn_exp2f(l2c * d2) * fn[r];
            }
            ssp[k] = s * c.w;
        }
        #pragma unroll
        for (int k = 0; k < 32; ++k)
            ssl[wave * M_ + lane + (k << 6)] = ssp[k];
        __syncthreads();
        for (int m = tid; m < M_; m += THREADS)
            atomicAdd(&ssc_g[b * M_ + m],
                      ssl[m] + ssl[M_ + m] + ssl[2*M_ + m] + ssl[3*M_ + m]);
    }
}

extern "C" void kernel_launch(void* const* d_in, const int* in_sizes, int n_in,
                              void* d_out, int out_size, void* d_ws, size_t ws_size,
                              hipStream_t stream) {
    const float* xyz1 = (const float*)d_in[0];
    const float* xyz2 = (const float*)d_in[1];
    float* out = (float*)d_out;
    float* ws = (float*)d_ws;
    const int SZ = B_ * N_;          // == B_*M_ == 16384
    float* rL  = ws;
    float* fb  = ws + SZ;
    float* rRb[2] = { ws + 2*SZ, ws + 3*SZ };
    float* ssb[3] = { ws + 4*SZ, ws + 5*SZ, ws + 6*SZ };

    init_kernel<<<(SZ + THREADS - 1) / THREADS, THREADS, 0, stream>>>(
        rL, fb, ssb[0], out);

    constexpr float LOG2E = 1.4426950408889634f;
    static const float levels[10] = {
        -16384.f, -4096.f, -1024.f, -256.f, -64.f,
        -16.f, -4.f, -1.f, -0.25f, 0.f
    };
    // kernel s (s=0..10): phase2 of step s-1 (if s>0) + phase1 of step s (if s<10)
    for (int s = 0; s <= 10; ++s) {
        const int has_p2 = (s > 0);
        const int has_p1 = (s < 10);
        const float l2p = has_p2 ? levels[s-1] * LOG2E : 0.f;
        const float l2c = has_p1 ? levels[s]   * LOG2E : 0.f;
        fused_step<<<GRID, THREADS, 0, stream>>>(
            xyz1, xyz2, rL, fb,
            rRb[(s + 1) & 1],      // rR(s-1)   (s>=1; unused at s=0)
            rRb[s & 1],            // rR(s) out
            ssb[(s + 2) % 3],      // ss(s-1)   (s>=1; unused at s=0)
            ssb[s % 3],            // ss(s) accumulate (pre-zeroed by kernel s-1 / init)
            ssb[(s + 1) % 3],      // ss(s+1) zeroed for next kernel
            out, l2p, l2c, has_p2, has_p1);
    }
}